// Round 23
// baseline (725.083 us; speedup 1.0000x reference)
//
#include <hip/hip_runtime.h>

typedef __bf16 bf16_t;
typedef __bf16 bf16x8 __attribute__((ext_vector_type(8)));
typedef __bf16 bf16x4 __attribute__((ext_vector_type(4)));
typedef __bf16 bf16x2 __attribute__((ext_vector_type(2)));
typedef float  f32x4  __attribute__((ext_vector_type(4)));
typedef unsigned int u32;
typedef u32 u32x4 __attribute__((ext_vector_type(4)));

#define T_TOK 8192
#define DIM   1024
#define DFF   4096
#define NEXP  8

__device__ __forceinline__ void gll16(const void* g, void* l) {
    __builtin_amdgcn_global_load_lds(
        (const __attribute__((address_space(1))) char*)g,
        (__attribute__((address_space(3))) char*)l, 16, 0, 0);
}

// ---------------- packed-pair transpose tile (64x64), u32 row-pair packing (r16-best) ----------------
__device__ __forceinline__ void transpose_tile(
    const float* __restrict__ src, bf16_t* __restrict__ dst,
    int R, int C, int r0, int c0, int tid, u32* lds)
{
    {
        int cg = tid & 15, rp = tid >> 4;     // cg: 4-col group, rp: 0..15
#pragma unroll
        for (int i = 0; i < 2; ++i) {
            int p = rp + i * 16;              // row-pair 0..31
            f32x4 a = *(const f32x4*)&src[(size_t)(r0 + 2 * p) * C + c0 + cg * 4];
            f32x4 b = *(const f32x4*)&src[(size_t)(r0 + 2 * p + 1) * C + c0 + cg * 4];
#pragma unroll
            for (int j = 0; j < 4; ++j) {
                int c = cg * 4 + j;
                union { bf16x2 h; u32 w; } cv;
                cv.h[0] = (bf16_t)a[j];       // even row -> low 16 (element 2p)
                cv.h[1] = (bf16_t)b[j];       // odd row  -> high 16 (element 2p+1)
                int ps = p ^ (((c >> 2) & 7) << 2);
                lds[c * 32 + ps] = cv.w;
            }
        }
    }
    __syncthreads();
    {
        int q = tid & 7, ccb = tid >> 3;      // q: 16B segment, ccb: 0..31
#pragma unroll
        for (int i = 0; i < 2; ++i) {
            int cc = ccb + i * 32;            // out-row = source col
            int ps = (q * 4) ^ ((((cc) >> 2) & 7) << 2);
            u32x4 v = *(const u32x4*)&lds[cc * 32 + ps];
            *(u32x4*)&dst[(size_t)(c0 + cc) * R + r0 + q * 8] = v;
        }
    }
}

// ---------------- fused prologue: router (0..2047, dispatched FIRST) + x->bf16
// (2048..4095) + w1 transpose (4096..12287). w2 transpose lives in GEMM1's launch.
__global__ __launch_bounds__(256) void fused_pre_kernel(
    const float* __restrict__ x, const float* __restrict__ noise,
    const float* __restrict__ w_route, const float* __restrict__ b_route,
    const float* __restrict__ w_noise, const float* __restrict__ b_noise,
    const float* __restrict__ w1,
    bf16_t* __restrict__ w1t, bf16_t* __restrict__ xb,
    int* __restrict__ counts, int* __restrict__ lists, float* __restrict__ gate_tok)
{
    __shared__ u32 lds[64 * 32];
    int id = blockIdx.x;
    int tid = threadIdx.x;

    if (id >= 4096) {
        int t1 = id - 4096;
        int e = t1 >> 10, rem = t1 & 1023;
        int bx = rem & 63, by = rem >> 6;               // DFF/64=64 x, DIM/64=16 y
        transpose_tile(w1 + (size_t)e * DIM * DFF, w1t + (size_t)e * DIM * DFF,
                       DIM, DFF, by * 64, bx * 64, tid, lds);
        return;
    }

    int wave = tid >> 6;
    int lane = tid & 63;

    if (id >= 2048) {
        // ---- x -> bf16: 4 tokens/block, 1 token/wave ----
        int tok = (id - 2048) * 4 + wave;
        const f32x4* src = (const f32x4*)(x + (size_t)tok * DIM);
        bf16x8* dst = (bf16x8*)(xb + (size_t)tok * DIM);
#pragma unroll
        for (int j = 0; j < 2; ++j) {
            int c = lane + j * 64;
            f32x4 a = src[c * 2 + 0];
            f32x4 b = src[c * 2 + 1];
            bf16x8 o;
            o[0] = (bf16_t)a[0]; o[1] = (bf16_t)a[1]; o[2] = (bf16_t)a[2]; o[3] = (bf16_t)a[3];
            o[4] = (bf16_t)b[0]; o[5] = (bf16_t)b[1]; o[6] = (bf16_t)b[2]; o[7] = (bf16_t)b[3];
            dst[c] = o;
        }
        return;
    }

    // ---- router: wave per token, f64 accumulation (r14 verbatim) ----
    int tok = id * 4 + wave;
    if (tok >= T_TOK) return;

    const float* xr = x + (size_t)tok * DIM;
    double aR[NEXP], aN[NEXP];
#pragma unroll
    for (int e = 0; e < NEXP; ++e) { aR[e] = 0.0; aN[e] = 0.0; }

#pragma unroll 4
    for (int i = 0; i < 16; ++i) {
        int k = lane + i * 64;
        double xv = (double)xr[k];
        const float4* wr4 = (const float4*)(w_route + (size_t)k * 8);
        const float4* wn4 = (const float4*)(w_noise + (size_t)k * 8);
        float4 r0 = wr4[0], r1 = wr4[1];
        float4 n0 = wn4[0], n1 = wn4[1];
        aR[0] += xv * (double)r0.x; aR[1] += xv * (double)r0.y;
        aR[2] += xv * (double)r0.z; aR[3] += xv * (double)r0.w;
        aR[4] += xv * (double)r1.x; aR[5] += xv * (double)r1.y;
        aR[6] += xv * (double)r1.z; aR[7] += xv * (double)r1.w;
        aN[0] += xv * (double)n0.x; aN[1] += xv * (double)n0.y;
        aN[2] += xv * (double)n0.z; aN[3] += xv * (double)n0.w;
        aN[4] += xv * (double)n1.x; aN[5] += xv * (double)n1.y;
        aN[6] += xv * (double)n1.z; aN[7] += xv * (double)n1.w;
    }
#pragma unroll
    for (int e = 0; e < NEXP; ++e) {
        for (int s = 1; s < 64; s <<= 1) {
            aR[e] += __shfl_xor(aR[e], s);
            aN[e] += __shfl_xor(aN[e], s);
        }
    }
    if (lane == 0) {
        double nv[NEXP];
#pragma unroll
        for (int e = 0; e < NEXP; ++e) {
            double lg = aR[e] + (double)b_route[e];
            double nl = aN[e] + (double)b_noise[e];
            double sp = (nl > 30.0) ? nl : log1p(exp(nl));
            nv[e] = lg + (double)noise[(size_t)tok * 8 + e] * sp;
        }
        int i1 = 0;
#pragma unroll
        for (int e = 1; e < NEXP; ++e) if (nv[e] > nv[i1]) i1 = e;
        int i2 = (i1 == 0) ? 1 : 0;
#pragma unroll
        for (int e = 0; e < NEXP; ++e) if (e != i1 && nv[e] > nv[i2]) i2 = e;
        double m = nv[i1];
        double e2 = exp(nv[i2] - m);
        double s = 1.0 + e2;
        gate_tok[2 * tok + 0] = (float)(1.0 / s);
        gate_tok[2 * tok + 1] = (float)(e2 / s);
        int p1 = atomicAdd(&counts[i1], 1);
        lists[i1 * T_TOK + p1] = 2 * tok + 0;
        int p2 = atomicAdd(&counts[i2], 1);
        lists[i2 * T_TOK + p2] = 2 * tok + 1;
    }
}

// ---------------- grouped GEMM: 128x128 tile, BK=64, 4 waves, counted-vmcnt dbuf ----------------
// r22-proven body. MODE 0: 1-D grid; ids >= 16384 = w2-transpose tiles
// (overlap GEMM1 compute); GEMM ids use the 8x8 supertile z-order (L2-exact
// 4MB concurrent set; FETCH 328->217MB verified r22). MODE 0 gathers A from
// xb via list; H written PACKED. bases inline. e = wg&7 clustering +
// vmcnt(8) + T2 swizzle + T5 setprio.
// MODE 1 (atomic fusion, this round): epilogue atomically accumulates
// gate*(acc+bias) into f32 out[token] — combine kernel + Yp eliminated.
// Each out element gets exactly 2 contributions (different blocks, possibly
// different XCDs); global atomicAdd is device-scope by default (m20) -> safe.
template<int K, int MODE>
__global__ __launch_bounds__(256) void moe_gemm_kernel(
    const bf16_t* __restrict__ Asrc, const bf16_t* __restrict__ Wt,
    const float* __restrict__ bias,
    const int* __restrict__ counts, const int* __restrict__ lists,
    const float* __restrict__ gate_tok,
    bf16_t* __restrict__ Hout, float* __restrict__ outp,
    const float* __restrict__ w2src, bf16_t* __restrict__ w2t)
{
    constexpr int N = (MODE == 0) ? DFF : DIM;
    constexpr int NT = K / 64;
    constexpr int NY = N / 128;

    __shared__ __attribute__((aligned(16))) bf16_t Ah0[128 * 64];
    __shared__ __attribute__((aligned(16))) bf16_t Bh0[128 * 64];
    __shared__ __attribute__((aligned(16))) bf16_t Ah1[128 * 64];
    __shared__ __attribute__((aligned(16))) bf16_t Bh1[128 * 64];

    int wg;
    if constexpr (MODE == 0) {
        wg = blockIdx.x;
        if (wg >= 16384) {
            // w2 [DFF][DIM] transpose tile (r16-proven), LDS aliased into Ah0
            int t2 = wg - 16384;
            int e = t2 >> 10, rem = t2 & 1023;
            int bx = rem & 15, by = rem >> 4;           // DIM/64=16 x, DFF/64=64 y
            transpose_tile(w2src + (size_t)e * DFF * DIM, w2t + (size_t)e * DFF * DIM,
                           DFF, DIM, by * 64, bx * 64, threadIdx.x, (u32*)Ah0);
            return;
        }
    } else {
        wg = blockIdx.x + 64 * (blockIdx.y + NY * blockIdx.z);
    }

    int e = wg & 7;
    int inner = wg >> 3;
    int xi, yi;
    if constexpr (MODE == 0) {
        // 8x8 supertile z-order: st = supertile (xg 8 x yg 4), s = slot in it
        int st = inner >> 6, s = inner & 63;
        xi = (st & 7) * 8 + (s & 7);    // 0..63
        yi = (st >> 3) * 8 + (s >> 3);  // 0..31
    } else {
        xi = inner & 63;
        yi = inner >> 6;
    }

    int cnt, base;
    {
        int s = 0, c = 0, b = 0;
#pragma unroll
        for (int i = 0; i < NEXP; ++i) {
            int ci = counts[i];
            if (i == e) { b = s; c = ci; }
            s += ci;
        }
        cnt = c; base = b;
    }
    int m0 = xi * 128;
    if (m0 >= cnt) return;
    int n0 = yi * 128;
    const int* list = lists + e * T_TOK;
    const bf16_t* W = Wt + (size_t)e * N * K;

    int tid = threadIdx.x;
    int lane = tid & 63;
    int wave = tid >> 6;
    int wr = wave >> 1, wc = wave & 1;

    int kcs = (((lane & 7) ^ (lane >> 3)) << 3);
    const bf16_t* pA[4];
    const bf16_t* pB[4];
#pragma unroll
    for (int i = 0; i < 4; ++i) {
        int c = wave * 4 + i;
        int r = c * 8 + (lane >> 3);
        int ridx = m0 + r; if (ridx > cnt - 1) ridx = cnt - 1;
        size_t arow;
        if constexpr (MODE == 0) arow = (size_t)(list[ridx] >> 1);   // gather from xb
        else                     arow = (size_t)(base + ridx);       // packed H
        pA[i] = Asrc + arow * K + kcs;
        pB[i] = W + (size_t)(n0 + r) * K + kcs;
    }

    f32x4 acc[4][4];
#pragma unroll
    for (int m = 0; m < 4; ++m)
#pragma unroll
        for (int n = 0; n < 4; ++n)
            acc[m][n] = (f32x4){0.f, 0.f, 0.f, 0.f};

    int g = lane >> 4, ln15 = lane & 15, ln7 = lane & 7;

#define STAGE(An, Bn, k0) do {                                               \
    _Pragma("unroll") for (int i = 0; i < 4; ++i) {                          \
        int c = wave * 4 + i;                                                \
        gll16(pA[i] + (k0), (An) + c * 512);                                 \
        gll16(pB[i] + (k0), (Bn) + c * 512);                                 \
    } } while (0)

#define COMPUTE(Ab, Bb) do {                                                 \
    _Pragma("unroll") for (int kk = 0; kk < 2; ++kk) {                       \
        bf16x8 a[4], b[4];                                                   \
        int sw = (((kk * 4 + g) ^ ln7) << 3);                                \
        _Pragma("unroll") for (int n = 0; n < 4; ++n)                        \
            b[n] = *(const bf16x8*)((Bb) + (wc * 64 + n * 16 + ln15) * 64 + sw); \
        _Pragma("unroll") for (int m = 0; m < 4; ++m)                        \
            a[m] = *(const bf16x8*)((Ab) + (wr * 64 + m * 16 + ln15) * 64 + sw); \
        __builtin_amdgcn_s_setprio(1);                                       \
        _Pragma("unroll") for (int m = 0; m < 4; ++m)                        \
            _Pragma("unroll") for (int n = 0; n < 4; ++n)                    \
                acc[m][n] = __builtin_amdgcn_mfma_f32_16x16x32_bf16(a[m], b[n], acc[m][n], 0, 0, 0); \
        __builtin_amdgcn_s_setprio(0);                                       \
    } } while (0)

#define FENCE() __builtin_amdgcn_sched_barrier(0)
#define WAITV(n) asm volatile("s_waitcnt vmcnt(" #n ")" ::: "memory")

    STAGE(Ah0, Bh0, 0);

    for (int kt = 0; kt < NT; kt += 2) {
        if (kt + 1 < NT) { STAGE(Ah1, Bh1, (kt + 1) * 64); WAITV(8); }
        else             { WAITV(0); }
        FENCE(); __builtin_amdgcn_s_barrier(); FENCE();
        COMPUTE(Ah0, Bh0);
        FENCE(); __builtin_amdgcn_s_barrier(); FENCE();
        if (kt + 2 < NT) { STAGE(Ah0, Bh0, (kt + 2) * 64); WAITV(8); }
        else             { WAITV(0); }
        FENCE(); __builtin_amdgcn_s_barrier(); FENCE();
        COMPUTE(Ah1, Bh1);
        FENCE(); __builtin_amdgcn_s_barrier(); FENCE();
    }
#undef STAGE
#undef COMPUTE
#undef FENCE
#undef WAITV

    int l4 = lane >> 4;
    float bs[4];
#pragma unroll
    for (int n = 0; n < 4; ++n)
        bs[n] = bias[e * N + n0 + wc * 64 + n * 16 + ln15];
#pragma unroll
    for (int m = 0; m < 4; ++m) {
#pragma unroll
        for (int j = 0; j < 4; ++j) {
            int grow = m0 + wr * 64 + m * 16 + l4 * 4 + j;
            if (grow >= cnt) continue;
            if constexpr (MODE == 0) {
#pragma unroll
                for (int n = 0; n < 4; ++n) {
                    int gcol = n0 + wc * 64 + n * 16 + ln15;
                    float v = acc[m][n][j] + bs[n];
                    Hout[(size_t)(base + grow) * DFF + gcol] = (bf16_t)fmaxf(v, 0.f);
                }
            } else {
                int entry = list[grow];
                float gt = gate_tok[entry];
                float* orow = outp + (size_t)(entry >> 1) * DIM;
#pragma unroll
                for (int n = 0; n < 4; ++n) {
                    int gcol = n0 + wc * 64 + n * 16 + ln15;
                    atomicAdd(&orow[gcol], gt * (acc[m][n][j] + bs[n]));
                }
            }
        }
    }
}

extern "C" void kernel_launch(void* const* d_in, const int* in_sizes, int n_in,
                              void* d_out, int out_size, void* d_ws, size_t ws_size,
                              hipStream_t stream) {
    const float* x       = (const float*)d_in[0];
    const float* noise   = (const float*)d_in[1];
    const float* w_route = (const float*)d_in[2];
    const float* b_route = (const float*)d_in[3];
    const float* w_noise = (const float*)d_in[4];
    const float* b_noise = (const float*)d_in[5];
    const float* w1      = (const float*)d_in[6];
    const float* b1      = (const float*)d_in[7];
    const float* w2      = (const float*)d_in[8];
    const float* b2      = (const float*)d_in[9];
    float* out = (float*)d_out;

    char* ws = (char*)d_ws;
    size_t off = 0;
    auto alloc = [&](size_t bytes) {
        off = (off + 255) & ~(size_t)255;
        size_t r = off; off += bytes; return r;
    };
    int*    counts   = (int*)   (ws + alloc(32));
    int*    lists    = (int*)   (ws + alloc((size_t)NEXP * T_TOK * 4));
    float*  gate_tok = (float*) (ws + alloc((size_t)T_TOK * 2 * 4));
    bf16_t* w1t      = (bf16_t*)(ws + alloc((size_t)NEXP * DFF * DIM * 2));
    bf16_t* w2t      = (bf16_t*)(ws + alloc((size_t)NEXP * DIM * DFF * 2));
    bf16_t* xb       = (bf16_t*)(ws + alloc((size_t)T_TOK * DIM * 2));
    bf16_t* H        = (bf16_t*)(ws + alloc((size_t)T_TOK * 2 * DFF * 2));
    (void)ws_size; (void)in_sizes; (void)n_in; (void)out_size;

    hipMemsetAsync(counts, 0, 32, stream);
    hipMemsetAsync(out, 0, (size_t)T_TOK * DIM * 4, stream);

    // router (0..2047, runs first) + x->bf16 (2048..4095) overlap the w1 transpose.
    fused_pre_kernel<<<12288, 256, 0, stream>>>(x, noise, w_route, b_route, w_noise, b_noise,
                                                w1, w1t, xb, counts, lists, gate_tok);

    // GEMM1 (ids 0..16383, 8x8-supertiled) + w2 transpose (ids 16384..24575) overlap.
    moe_gemm_kernel<DIM, 0><<<24576, 256, 0, stream>>>(
        xb, w1t, b1, counts, lists, gate_tok, H, nullptr, w2, w2t);
    // GEMM2: gate-scaled atomic accumulate directly into f32 out (combine fused).
    moe_gemm_kernel<DFF, 1><<<dim3(64, DIM / 128, NEXP), 256, 0, stream>>>(
        H, w2t, b2, counts, lists, gate_tok, nullptr, out, nullptr, nullptr);
}

// Round 24
// 692.255 us; speedup vs baseline: 1.0474x; 1.0474x over previous
//
#include <hip/hip_runtime.h>

typedef __bf16 bf16_t;
typedef __bf16 bf16x8 __attribute__((ext_vector_type(8)));
typedef __bf16 bf16x4 __attribute__((ext_vector_type(4)));
typedef __bf16 bf16x2 __attribute__((ext_vector_type(2)));
typedef float  f32x4  __attribute__((ext_vector_type(4)));
typedef unsigned int u32;
typedef u32 u32x4 __attribute__((ext_vector_type(4)));

#define T_TOK 8192
#define DIM   1024
#define DFF   4096
#define NEXP  8

__device__ __forceinline__ void gll16(const void* g, void* l) {
    __builtin_amdgcn_global_load_lds(
        (const __attribute__((address_space(1))) char*)g,
        (__attribute__((address_space(3))) char*)l, 16, 0, 0);
}

// ---------------- packed-pair transpose tile (64x64), u32 row-pair packing (r16-best) ----------------
__device__ __forceinline__ void transpose_tile(
    const float* __restrict__ src, bf16_t* __restrict__ dst,
    int R, int C, int r0, int c0, int tid, u32* lds)
{
    {
        int cg = tid & 15, rp = tid >> 4;     // cg: 4-col group, rp: 0..15
#pragma unroll
        for (int i = 0; i < 2; ++i) {
            int p = rp + i * 16;              // row-pair 0..31
            f32x4 a = *(const f32x4*)&src[(size_t)(r0 + 2 * p) * C + c0 + cg * 4];
            f32x4 b = *(const f32x4*)&src[(size_t)(r0 + 2 * p + 1) * C + c0 + cg * 4];
#pragma unroll
            for (int j = 0; j < 4; ++j) {
                int c = cg * 4 + j;
                union { bf16x2 h; u32 w; } cv;
                cv.h[0] = (bf16_t)a[j];       // even row -> low 16 (element 2p)
                cv.h[1] = (bf16_t)b[j];       // odd row  -> high 16 (element 2p+1)
                int ps = p ^ (((c >> 2) & 7) << 2);
                lds[c * 32 + ps] = cv.w;
            }
        }
    }
    __syncthreads();
    {
        int q = tid & 7, ccb = tid >> 3;      // q: 16B segment, ccb: 0..31
#pragma unroll
        for (int i = 0; i < 2; ++i) {
            int cc = ccb + i * 32;            // out-row = source col
            int ps = (q * 4) ^ ((((cc) >> 2) & 7) << 2);
            u32x4 v = *(const u32x4*)&lds[cc * 32 + ps];
            *(u32x4*)&dst[(size_t)(c0 + cc) * R + r0 + q * 8] = v;
        }
    }
}

// ---------------- fused prologue: router (0..2047, dispatched FIRST) + x->bf16
// (2048..4095) + w1 transpose (4096..12287). w2 transpose lives in GEMM1's launch.
__global__ __launch_bounds__(256) void fused_pre_kernel(
    const float* __restrict__ x, const float* __restrict__ noise,
    const float* __restrict__ w_route, const float* __restrict__ b_route,
    const float* __restrict__ w_noise, const float* __restrict__ b_noise,
    const float* __restrict__ w1,
    bf16_t* __restrict__ w1t, bf16_t* __restrict__ xb,
    int* __restrict__ counts, int* __restrict__ lists, float* __restrict__ gate_tok,
    int* __restrict__ inv)
{
    __shared__ u32 lds[64 * 32];
    int id = blockIdx.x;
    int tid = threadIdx.x;

    if (id >= 4096) {
        int t1 = id - 4096;
        int e = t1 >> 10, rem = t1 & 1023;
        int bx = rem & 63, by = rem >> 6;               // DFF/64=64 x, DIM/64=16 y
        transpose_tile(w1 + (size_t)e * DIM * DFF, w1t + (size_t)e * DIM * DFF,
                       DIM, DFF, by * 64, bx * 64, tid, lds);
        return;
    }

    int wave = tid >> 6;
    int lane = tid & 63;

    if (id >= 2048) {
        // ---- x -> bf16: 4 tokens/block, 1 token/wave ----
        int tok = (id - 2048) * 4 + wave;
        const f32x4* src = (const f32x4*)(x + (size_t)tok * DIM);
        bf16x8* dst = (bf16x8*)(xb + (size_t)tok * DIM);
#pragma unroll
        for (int j = 0; j < 2; ++j) {
            int c = lane + j * 64;
            f32x4 a = src[c * 2 + 0];
            f32x4 b = src[c * 2 + 1];
            bf16x8 o;
            o[0] = (bf16_t)a[0]; o[1] = (bf16_t)a[1]; o[2] = (bf16_t)a[2]; o[3] = (bf16_t)a[3];
            o[4] = (bf16_t)b[0]; o[5] = (bf16_t)b[1]; o[6] = (bf16_t)b[2]; o[7] = (bf16_t)b[3];
            dst[c] = o;
        }
        return;
    }

    // ---- router: wave per token, f64 accumulation (r14 verbatim + inv write) ----
    int tok = id * 4 + wave;
    if (tok >= T_TOK) return;

    const float* xr = x + (size_t)tok * DIM;
    double aR[NEXP], aN[NEXP];
#pragma unroll
    for (int e = 0; e < NEXP; ++e) { aR[e] = 0.0; aN[e] = 0.0; }

#pragma unroll 4
    for (int i = 0; i < 16; ++i) {
        int k = lane + i * 64;
        double xv = (double)xr[k];
        const float4* wr4 = (const float4*)(w_route + (size_t)k * 8);
        const float4* wn4 = (const float4*)(w_noise + (size_t)k * 8);
        float4 r0 = wr4[0], r1 = wr4[1];
        float4 n0 = wn4[0], n1 = wn4[1];
        aR[0] += xv * (double)r0.x; aR[1] += xv * (double)r0.y;
        aR[2] += xv * (double)r0.z; aR[3] += xv * (double)r0.w;
        aR[4] += xv * (double)r1.x; aR[5] += xv * (double)r1.y;
        aR[6] += xv * (double)r1.z; aR[7] += xv * (double)r1.w;
        aN[0] += xv * (double)n0.x; aN[1] += xv * (double)n0.y;
        aN[2] += xv * (double)n0.z; aN[3] += xv * (double)n0.w;
        aN[4] += xv * (double)n1.x; aN[5] += xv * (double)n1.y;
        aN[6] += xv * (double)n1.z; aN[7] += xv * (double)n1.w;
    }
#pragma unroll
    for (int e = 0; e < NEXP; ++e) {
        for (int s = 1; s < 64; s <<= 1) {
            aR[e] += __shfl_xor(aR[e], s);
            aN[e] += __shfl_xor(aN[e], s);
        }
    }
    if (lane == 0) {
        double nv[NEXP];
#pragma unroll
        for (int e = 0; e < NEXP; ++e) {
            double lg = aR[e] + (double)b_route[e];
            double nl = aN[e] + (double)b_noise[e];
            double sp = (nl > 30.0) ? nl : log1p(exp(nl));
            nv[e] = lg + (double)noise[(size_t)tok * 8 + e] * sp;
        }
        int i1 = 0;
#pragma unroll
        for (int e = 1; e < NEXP; ++e) if (nv[e] > nv[i1]) i1 = e;
        int i2 = (i1 == 0) ? 1 : 0;
#pragma unroll
        for (int e = 0; e < NEXP; ++e) if (e != i1 && nv[e] > nv[i2]) i2 = e;
        double m = nv[i1];
        double e2 = exp(nv[i2] - m);
        double s = 1.0 + e2;
        gate_tok[2 * tok + 0] = (float)(1.0 / s);
        gate_tok[2 * tok + 1] = (float)(e2 / s);
        int p1 = atomicAdd(&counts[i1], 1);
        lists[i1 * T_TOK + p1] = 2 * tok + 0;
        inv[2 * tok + 0] = (i1 << 13) | p1;
        int p2 = atomicAdd(&counts[i2], 1);
        lists[i2 * T_TOK + p2] = 2 * tok + 1;
        inv[2 * tok + 1] = (i2 << 13) | p2;
    }
}

// ---------------- grouped GEMM: 128x128 tile, BK=64, 4 waves, counted-vmcnt dbuf ----------------
// r21-proven body. MODE 0: 1-D grid; ids >= 16384 = w2-transpose tiles
// (overlap GEMM1 compute); GEMM ids use an 8x8 SUPERTILE z-order so the 64
// concurrently-resident blocks per XCD touch 8 A-tiles (2MB) + 8 B-panels
// (2MB) = 4MB = exactly one XCD L2 (FETCH 328->217MB verified r22).
// MODE 0 gathers A from xb; H written PACKED. bases inline.
// e = wg&7 clustering + vmcnt(8) + T2 swizzle + T5 setprio.
template<int K, int MODE>
__global__ __launch_bounds__(256) void moe_gemm_kernel(
    const bf16_t* __restrict__ Asrc, const bf16_t* __restrict__ Wt,
    const float* __restrict__ bias,
    const int* __restrict__ counts, const int* __restrict__ lists,
    const float* __restrict__ gate_tok,
    bf16_t* __restrict__ Hout, bf16_t* __restrict__ Yp,
    const float* __restrict__ w2src, bf16_t* __restrict__ w2t)
{
    constexpr int N = (MODE == 0) ? DFF : DIM;
    constexpr int NT = K / 64;
    constexpr int NY = N / 128;

    __shared__ __attribute__((aligned(16))) bf16_t Ah0[128 * 64];
    __shared__ __attribute__((aligned(16))) bf16_t Bh0[128 * 64];
    __shared__ __attribute__((aligned(16))) bf16_t Ah1[128 * 64];
    __shared__ __attribute__((aligned(16))) bf16_t Bh1[128 * 64];

    int wg;
    if constexpr (MODE == 0) {
        wg = blockIdx.x;
        if (wg >= 16384) {
            // w2 [DFF][DIM] transpose tile (r16-proven), LDS aliased into Ah0
            int t2 = wg - 16384;
            int e = t2 >> 10, rem = t2 & 1023;
            int bx = rem & 15, by = rem >> 4;           // DIM/64=16 x, DFF/64=64 y
            transpose_tile(w2src + (size_t)e * DFF * DIM, w2t + (size_t)e * DFF * DIM,
                           DFF, DIM, by * 64, bx * 64, threadIdx.x, (u32*)Ah0);
            return;
        }
    } else {
        wg = blockIdx.x + 64 * (blockIdx.y + NY * blockIdx.z);
    }

    int e = wg & 7;
    int inner = wg >> 3;
    int xi, yi;
    if constexpr (MODE == 0) {
        // 8x8 supertile z-order: st = supertile (xg 8 x yg 4), s = slot in it
        int st = inner >> 6, s = inner & 63;
        xi = (st & 7) * 8 + (s & 7);    // 0..63
        yi = (st >> 3) * 8 + (s >> 3);  // 0..31
    } else {
        xi = inner & 63;
        yi = inner >> 6;
    }

    int cnt, base;
    {
        int s = 0, c = 0, b = 0;
#pragma unroll
        for (int i = 0; i < NEXP; ++i) {
            int ci = counts[i];
            if (i == e) { b = s; c = ci; }
            s += ci;
        }
        cnt = c; base = b;
    }
    int m0 = xi * 128;
    if (m0 >= cnt) return;
    int n0 = yi * 128;
    const int* list = lists + e * T_TOK;
    const bf16_t* W = Wt + (size_t)e * N * K;

    int tid = threadIdx.x;
    int lane = tid & 63;
    int wave = tid >> 6;
    int wr = wave >> 1, wc = wave & 1;

    int kcs = (((lane & 7) ^ (lane >> 3)) << 3);
    const bf16_t* pA[4];
    const bf16_t* pB[4];
#pragma unroll
    for (int i = 0; i < 4; ++i) {
        int c = wave * 4 + i;
        int r = c * 8 + (lane >> 3);
        int ridx = m0 + r; if (ridx > cnt - 1) ridx = cnt - 1;
        size_t arow;
        if constexpr (MODE == 0) arow = (size_t)(list[ridx] >> 1);   // gather from xb
        else                     arow = (size_t)(base + ridx);       // packed H
        pA[i] = Asrc + arow * K + kcs;
        pB[i] = W + (size_t)(n0 + r) * K + kcs;
    }

    f32x4 acc[4][4];
#pragma unroll
    for (int m = 0; m < 4; ++m)
#pragma unroll
        for (int n = 0; n < 4; ++n)
            acc[m][n] = (f32x4){0.f, 0.f, 0.f, 0.f};

    int g = lane >> 4, ln15 = lane & 15, ln7 = lane & 7;

#define STAGE(An, Bn, k0) do {                                               \
    _Pragma("unroll") for (int i = 0; i < 4; ++i) {                          \
        int c = wave * 4 + i;                                                \
        gll16(pA[i] + (k0), (An) + c * 512);                                 \
        gll16(pB[i] + (k0), (Bn) + c * 512);                                 \
    } } while (0)

#define COMPUTE(Ab, Bb) do {                                                 \
    _Pragma("unroll") for (int kk = 0; kk < 2; ++kk) {                       \
        bf16x8 a[4], b[4];                                                   \
        int sw = (((kk * 4 + g) ^ ln7) << 3);                                \
        _Pragma("unroll") for (int n = 0; n < 4; ++n)                        \
            b[n] = *(const bf16x8*)((Bb) + (wc * 64 + n * 16 + ln15) * 64 + sw); \
        _Pragma("unroll") for (int m = 0; m < 4; ++m)                        \
            a[m] = *(const bf16x8*)((Ab) + (wr * 64 + m * 16 + ln15) * 64 + sw); \
        __builtin_amdgcn_s_setprio(1);                                       \
        _Pragma("unroll") for (int m = 0; m < 4; ++m)                        \
            _Pragma("unroll") for (int n = 0; n < 4; ++n)                    \
                acc[m][n] = __builtin_amdgcn_mfma_f32_16x16x32_bf16(a[m], b[n], acc[m][n], 0, 0, 0); \
        __builtin_amdgcn_s_setprio(0);                                       \
    } } while (0)

#define FENCE() __builtin_amdgcn_sched_barrier(0)
#define WAITV(n) asm volatile("s_waitcnt vmcnt(" #n ")" ::: "memory")

    STAGE(Ah0, Bh0, 0);

    for (int kt = 0; kt < NT; kt += 2) {
        if (kt + 1 < NT) { STAGE(Ah1, Bh1, (kt + 1) * 64); WAITV(8); }
        else             { WAITV(0); }
        FENCE(); __builtin_amdgcn_s_barrier(); FENCE();
        COMPUTE(Ah0, Bh0);
        FENCE(); __builtin_amdgcn_s_barrier(); FENCE();
        if (kt + 2 < NT) { STAGE(Ah0, Bh0, (kt + 2) * 64); WAITV(8); }
        else             { WAITV(0); }
        FENCE(); __builtin_amdgcn_s_barrier(); FENCE();
        COMPUTE(Ah1, Bh1);
        FENCE(); __builtin_amdgcn_s_barrier(); FENCE();
    }
#undef STAGE
#undef COMPUTE
#undef FENCE
#undef WAITV

    int l4 = lane >> 4;
    float bs[4];
#pragma unroll
    for (int n = 0; n < 4; ++n)
        bs[n] = bias[e * N + n0 + wc * 64 + n * 16 + ln15];
#pragma unroll
    for (int m = 0; m < 4; ++m) {
#pragma unroll
        for (int j = 0; j < 4; ++j) {
            int grow = m0 + wr * 64 + m * 16 + l4 * 4 + j;
            if (grow >= cnt) continue;
            if constexpr (MODE == 0) {
#pragma unroll
                for (int n = 0; n < 4; ++n) {
                    int gcol = n0 + wc * 64 + n * 16 + ln15;
                    float v = acc[m][n][j] + bs[n];
                    Hout[(size_t)(base + grow) * DFF + gcol] = (bf16_t)fmaxf(v, 0.f);
                }
            } else {
                float gt = gate_tok[list[grow]];
#pragma unroll
                for (int n = 0; n < 4; ++n) {
                    int gcol = n0 + wc * 64 + n * 16 + ln15;
                    Yp[(size_t)(base + grow) * DIM + gcol] = (bf16_t)(gt * (acc[m][n][j] + bs[n]));
                }
            }
        }
    }
}

// ---------------- combine: out[t] = Yp[p0] + Yp[p1]; p from inv (e,pos) + inline bases ----------------
__global__ __launch_bounds__(256) void combine_kernel(
    const bf16_t* __restrict__ Yp, const int* __restrict__ inv,
    const int* __restrict__ counts, float* __restrict__ out)
{
    int bs[NEXP];
    {
        int s = 0;
#pragma unroll
        for (int i = 0; i < NEXP; ++i) { bs[i] = s; s += counts[i]; }
    }
    int q = threadIdx.x >> 7, i = threadIdx.x & 127;
    int t = blockIdx.x * 2 + q;
    int v0 = inv[2 * t], v1 = inv[2 * t + 1];
    int p0 = bs[v0 >> 13] + (v0 & 8191);
    int p1 = bs[v1 >> 13] + (v1 & 8191);
    bf16x8 va = ((const bf16x8*)(Yp + (size_t)p0 * DIM))[i];
    bf16x8 vb = ((const bf16x8*)(Yp + (size_t)p1 * DIM))[i];
    f32x4 o0, o1;
#pragma unroll
    for (int j = 0; j < 4; ++j) {
        o0[j] = (float)va[j] + (float)vb[j];
        o1[j] = (float)va[4 + j] + (float)vb[4 + j];
    }
    f32x4* o = (f32x4*)(out + (size_t)t * DIM + i * 8);
    o[0] = o0;
    o[1] = o1;
}

extern "C" void kernel_launch(void* const* d_in, const int* in_sizes, int n_in,
                              void* d_out, int out_size, void* d_ws, size_t ws_size,
                              hipStream_t stream) {
    const float* x       = (const float*)d_in[0];
    const float* noise   = (const float*)d_in[1];
    const float* w_route = (const float*)d_in[2];
    const float* b_route = (const float*)d_in[3];
    const float* w_noise = (const float*)d_in[4];
    const float* b_noise = (const float*)d_in[5];
    const float* w1      = (const float*)d_in[6];
    const float* b1      = (const float*)d_in[7];
    const float* w2      = (const float*)d_in[8];
    const float* b2      = (const float*)d_in[9];
    float* out = (float*)d_out;

    char* ws = (char*)d_ws;
    size_t off = 0;
    auto alloc = [&](size_t bytes) {
        off = (off + 255) & ~(size_t)255;
        size_t r = off; off += bytes; return r;
    };
    int*    counts   = (int*)   (ws + alloc(32));
    int*    lists    = (int*)   (ws + alloc((size_t)NEXP * T_TOK * 4));
    float*  gate_tok = (float*) (ws + alloc((size_t)T_TOK * 2 * 4));
    int*    inv      = (int*)   (ws + alloc((size_t)T_TOK * 2 * 4));
    bf16_t* w1t      = (bf16_t*)(ws + alloc((size_t)NEXP * DFF * DIM * 2));
    bf16_t* w2t      = (bf16_t*)(ws + alloc((size_t)NEXP * DIM * DFF * 2));
    bf16_t* xb       = (bf16_t*)(ws + alloc((size_t)T_TOK * DIM * 2));
    bf16_t* H        = (bf16_t*)(ws + alloc((size_t)T_TOK * 2 * DFF * 2));
    bf16_t* Yp       = w1t;   // w1t (64MB) dead after GEMM1; Yp bf16 (32MB)
    (void)ws_size; (void)in_sizes; (void)n_in; (void)out_size;

    hipMemsetAsync(counts, 0, 32, stream);

    // router (0..2047, runs first) + x->bf16 (2048..4095) overlap the w1 transpose.
    fused_pre_kernel<<<12288, 256, 0, stream>>>(x, noise, w_route, b_route, w_noise, b_noise,
                                                w1, w1t, xb, counts, lists, gate_tok, inv);

    // GEMM1 (ids 0..16383, 8x8-supertiled) + w2 transpose (ids 16384..24575) overlap.
    moe_gemm_kernel<DIM, 0><<<24576, 256, 0, stream>>>(
        xb, w1t, b1, counts, lists, gate_tok, H, nullptr, w2, w2t);
    moe_gemm_kernel<DFF, 1><<<dim3(64, DIM / 128, NEXP), 256, 0, stream>>>(
        H, w2t, b2, counts, lists, gate_tok, nullptr, Yp, nullptr, nullptr);

    combine_kernel<<<T_TOK / 2, 256, 0, stream>>>(Yp, inv, counts, out);
}